// Round 1
// baseline (361.980 us; speedup 1.0000x reference)
//
#include <hip/hip_runtime.h>

typedef unsigned short u16;
typedef unsigned int u32;
typedef __attribute__((ext_vector_type(8))) short short8;
typedef __attribute__((ext_vector_type(4))) float f32x4;

__device__ __forceinline__ u16 f2bf(float f) {
  u32 u = __float_as_uint(f);
  u += 0x7FFFu + ((u >> 16) & 1u);
  return (u16)(u >> 16);
}

// swizzled byte offset inside a [rows][128 bf16] (256B-stride) LDS tile
__device__ __forceinline__ int swz(int row, int inrow_byte) {
  return (row * 256 + inrow_byte) ^ ((row & 7) << 4);
}

// ---- prep: weights -> bf16 transposed [n][k] in ws ----
// ws (u16): [0,65536): layers 1..4: layer*16384 + n*128 + k  (W1 k-padded 48->128)
//           [65536,67584): W5T: n*128 + k  (16 cols, 4 real)
__global__ void prep_weights(const float* __restrict__ W1, const float* __restrict__ W2,
                             const float* __restrict__ W3, const float* __restrict__ W4,
                             const float* __restrict__ W5, u16* __restrict__ ws) {
  int idx = blockIdx.x * 256 + threadIdx.x;
  if (idx < 65536) {
    int layer = idx >> 14, rem = idx & 16383;
    int n = rem >> 7, k = rem & 127;
    float v;
    if (layer == 0)      v = (k < 48) ? W1[k * 128 + n] : 0.f;
    else if (layer == 1) v = W2[k * 128 + n];
    else if (layer == 2) v = W3[k * 128 + n];
    else                 v = W4[k * 128 + n];
    ws[idx] = f2bf(v);
  } else if (idx < 67584) {
    int i2 = idx - 65536;
    int n = i2 >> 7, k = i2 & 127;
    ws[idx] = f2bf((n < 4) ? W5[k * 4 + n] : 0.f);
  }
}

__global__ __launch_bounds__(256) void domino_main(
    const float* __restrict__ qp, const float* __restrict__ pts,
    const float* __restrict__ freqs,
    const float* __restrict__ b1, const float* __restrict__ b2,
    const float* __restrict__ b3, const float* __restrict__ b4,
    const float* __restrict__ b5, const int* __restrict__ mapping,
    const u16* __restrict__ wsW, float* __restrict__ out) {
  __shared__ alignas(16) u16 Abuf[64 * 128];    // 16KB activations (bf16, swizzled)
  __shared__ alignas(16) u16 Wbuf[128 * 128];   // 32KB current-layer W^T (bf16, swizzled)
  char* const ab = (char*)Abuf;
  char* const wb = (char*)Wbuf;

  const int tid  = threadIdx.x;
  const int lane = tid & 63;
  const int wid  = tid >> 6;
  const int blk  = blockIdx.x;
  const int l15  = lane & 15;
  const int lk   = lane >> 4;

  // ---- zero A (pad region for k>=48) ----
  {
    f32x4 z = {0.f, 0.f, 0.f, 0.f};
    #pragma unroll
    for (int c = 0; c < 4; ++c)
      *(f32x4*)(ab + c * 4096 + tid * 16) = z;
  }
  __syncthreads();

  // ---- gather + fourier features: rows r = q*8 + neighbor ----
  {
    const int r = tid >> 2, p = tid & 3;
    const int mg = blk * 8 + (r >> 3);
    const int nb = mapping[blk * 64 + r];
    float rel[3];
    #pragma unroll
    for (int d = 0; d < 3; ++d) rel[d] = pts[nb * 3 + d] - qp[mg * 3 + d];
    #pragma unroll
    for (int f2 = 0; f2 < 2; ++f2) {
      const int f = p * 2 + f2;
      const float fr = freqs[f];
      #pragma unroll
      for (int d = 0; d < 3; ++d) {
        float s, c;
        sincosf(rel[d] * fr, &s, &c);
        const int j = f * 3 + d;                       // matches (..,F,D) reshape: f*3+d
        *(u16*)(ab + swz(r, j * 2))        = f2bf(s);  // sin -> [0,24)
        *(u16*)(ab + swz(r, (24 + j) * 2)) = f2bf(c);  // cos -> [24,48)
      }
    }
  }

  const int RB0 = (wid & 1) * 32;     // wave's 32-row band
  const int CB0 = (wid >> 1) * 64;    // wave's 64-col band
  const float* const BS[4] = {b1, b2, b3, b4};

  #pragma unroll
  for (int layer = 0; layer < 4; ++layer) {
    // stage W^T[layer] -> Wbuf, swizzling on the ds-write side
    {
      const char* src = (const char*)(wsW + layer * 16384);
      #pragma unroll
      for (int c = 0; c < 8; ++c) {
        const int off = c * 4096 + tid * 16;
        const int n = off >> 8;
        f32x4 v = *(const f32x4*)(src + off);
        *(f32x4*)(wb + (off ^ ((n & 7) << 4))) = v;
      }
    }
    __syncthreads();   // staging + (iter0) features + prev writeback visible

    f32x4 acc[2][4];
    #pragma unroll
    for (int cb = 0; cb < 4; ++cb) {
      const float bv = BS[layer][CB0 + cb * 16 + l15];
      #pragma unroll
      for (int rb = 0; rb < 2; ++rb) {
        f32x4 bb = {bv, bv, bv, bv};
        acc[rb][cb] = bb;
      }
    }
    const int KKn = (layer == 0) ? 2 : 4;   // layer0: K=48 (padded to 64)
    #pragma unroll
    for (int kk = 0; kk < 4; ++kk) {
      if (kk < KKn) {
        short8 af[2];
        #pragma unroll
        for (int rb = 0; rb < 2; ++rb) {
          const int row = RB0 + rb * 16 + l15;
          af[rb] = *(const short8*)(ab + swz(row, kk * 64 + lk * 16));
        }
        #pragma unroll
        for (int cb = 0; cb < 4; ++cb) {
          const int n = CB0 + cb * 16 + l15;
          const short8 bfrag = *(const short8*)(wb + swz(n, kk * 64 + lk * 16));
          #pragma unroll
          for (int rb = 0; rb < 2; ++rb)
            acc[rb][cb] = __builtin_amdgcn_mfma_f32_16x16x32_bf16(af[rb], bfrag, acc[rb][cb], 0, 0, 0);
        }
      }
    }
    __syncthreads();   // everyone done reading A & W before A is overwritten

    // exact GELU + bf16 writeback into A  (C/D map: col=lane&15, row=(lane>>4)*4+reg)
    #pragma unroll
    for (int rb = 0; rb < 2; ++rb) {
      #pragma unroll
      for (int rg = 0; rg < 4; ++rg) {
        const int row = RB0 + rb * 16 + lk * 4 + rg;
        #pragma unroll
        for (int cb = 0; cb < 4; ++cb) {
          const float x = acc[rb][cb][rg];
          const float g = 0.5f * x * (1.0f + erff(x * 0.70710678118654752f));
          *(u16*)(ab + swz(row, (CB0 + cb * 16 + l15) * 2)) = f2bf(g);
        }
      }
    }
  }

  // ---- layer 5: [64x128] @ W5T[16x128], then mean over 8 neighbors ----
  {
    const char* src = (const char*)(wsW + 65536);
    const int off = tid * 16;            // 4KB total
    const int n = off >> 8;
    f32x4 v = *(const f32x4*)(src + off);
    *(f32x4*)(wb + (off ^ ((n & 7) << 4))) = v;
  }
  __syncthreads();   // also makes layer-4 writeback visible

  f32x4 acc5 = {0.f, 0.f, 0.f, 0.f};
  #pragma unroll
  for (int kk = 0; kk < 4; ++kk) {
    const int row = wid * 16 + l15;      // each wave: its own 16 rows x 16 cols
    const short8 a = *(const short8*)(ab + swz(row, kk * 64 + lk * 16));
    const short8 b = *(const short8*)(wb + swz(l15, kk * 64 + lk * 16));
    acc5 = __builtin_amdgcn_mfma_f32_16x16x32_bf16(a, b, acc5, 0, 0, 0);
  }
  // lane holds rows (lk*4 + 0..3) of its 16-row tile at col l15:
  // sum 4 in-lane rows, then xor-16 pairs rows {0-7}|{8-15} -> per-query sums
  float s4 = acc5[0] + acc5[1] + acc5[2] + acc5[3];
  s4 += __shfl_xor(s4, 16, 64);
  if (((lane >> 4) & 1) == 0 && l15 < 4) {
    const int q = wid * 2 + (lane >> 5);
    out[(blk * 8 + q) * 4 + l15] = 0.125f * s4 + b5[l15];
  }
}

extern "C" void kernel_launch(void* const* d_in, const int* in_sizes, int n_in,
                              void* d_out, int out_size, void* d_ws, size_t ws_size,
                              hipStream_t stream) {
  const float* qp      = (const float*)d_in[0];
  const float* pts     = (const float*)d_in[1];
  const float* freqs   = (const float*)d_in[2];
  const float* W1      = (const float*)d_in[3];
  const float* b1      = (const float*)d_in[4];
  const float* W2      = (const float*)d_in[5];
  const float* b2      = (const float*)d_in[6];
  const float* W3      = (const float*)d_in[7];
  const float* b3      = (const float*)d_in[8];
  const float* W4      = (const float*)d_in[9];
  const float* b4      = (const float*)d_in[10];
  const float* W5      = (const float*)d_in[11];
  const float* b5      = (const float*)d_in[12];
  const int*   mapping = (const int*)d_in[13];
  u16* ws = (u16*)d_ws;
  float* out = (float*)d_out;

  // 67584 u16 elements to fill: 264 blocks x 256 threads
  prep_weights<<<dim3(264), dim3(256), 0, stream>>>(W1, W2, W3, W4, W5, ws);
  // 131072 queries / 8 per block = 16384 blocks
  domino_main<<<dim3(16384), dim3(256), 0, stream>>>(
      qp, pts, freqs, b1, b2, b3, b4, b5, mapping, ws, out);
}